// Round 6
// baseline (192.532 us; speedup 1.0000x reference)
//
#include <hip/hip_runtime.h>
#include <stdint.h>

// Problem constants
#define NUM_C 1000
#define NB    4096
#define NCOL  9192          // NB + NUM_C + NO
#define NPAD  9216          // 288 row-tiles of 32
#define DK    512
#define BM    128
#define BN    256
#define INV_T 10.0f

typedef __attribute__((ext_vector_type(16))) float f32x16;
typedef __attribute__((ext_vector_type(8)))  int   i32x8;

// workspace layout (bytes)
// fall: MX fragment layout [tile=288][kq=8][chunk16B=128(swizzled)] = 4,718,592 B
//   lane l of a tile holds row (l&31), k = kq*64 + (l>>5)*32 + [0..31]
//   chunk swizzle within each 2048B kq-slab: phys p = c ^ ((c>>3)&7)  (involution)
#define OFF_FALL  0u
#define OFF_CNT   4718592u           // uint[1024] final hist (targets+pseudo)
#define OFF_CNTT  4722688u           // uint[1024] final hist (targets only)
#define OFF_S     4726784u           // float[4096]
#define OFF_P     4743168u           // float[4096]  (contiguous after S)

#define NCHUNKBLK 1152               // blocks doing fall chunks

__device__ __forceinline__ void async16(const void* g, void* l) {
  __builtin_amdgcn_global_load_lds((const __attribute__((address_space(1))) void*)g,
                                   (__attribute__((address_space(3))) void*)l,
                                   16, 0, 0);
}

// f32 -> e4m3fn (OCP), software RNE fallback
__device__ __forceinline__ unsigned sw_e4m3(float x) {
  float ax = fabsf(x);
  unsigned s = (__float_as_uint(x) >> 24) & 0x80u;
  if (ax < 0.015625f) {
    int n = (int)rintf(ax * 512.0f);
    if (n >= 8) return s | 0x08u;
    return s | (unsigned)n;
  }
  if (ax >= 448.0f) return s | 0x7Eu;
  unsigned u = __float_as_uint(ax);
  int ee = (int)(u >> 23) - 127;
  float scale = __uint_as_float((unsigned)(3 - ee + 127) << 23);
  int qv = (int)rintf(ax * scale);
  if (qv == 16) { ee++; qv = 8; }
  return s | (unsigned)(((ee + 7) << 3) | (qv - 8));
}

template <bool HI>
__device__ __forceinline__ int cvt2(float a, float b, int old) {
#if __has_builtin(__builtin_amdgcn_cvt_pk_fp8_f32)
  return __builtin_amdgcn_cvt_pk_fp8_f32(a, b, old, HI);
#else
  unsigned pk = sw_e4m3(a) | (sw_e4m3(b) << 8);
  return HI ? (int)(((unsigned)old & 0x0000FFFFu) | (pk << 16))
            : (int)(((unsigned)old & 0xFFFF0000u) | pk);
#endif
}

__device__ __forceinline__ i32x8 mk8(uint4 lo, uint4 hi) {
  i32x8 r;
  r[0] = (int)lo.x; r[1] = (int)lo.y; r[2] = (int)lo.z; r[3] = (int)lo.w;
  r[4] = (int)hi.x; r[5] = (int)hi.y; r[6] = (int)hi.z; r[7] = (int)hi.w;
  return r;
}

// MX-scaled fp8 MFMA, unit scales (e8m0 127 = 1.0): same products as plain fp8
#define MFMA_SC(a, b, c) \
  __builtin_amdgcn_mfma_scale_f32_32x32x64_f8f6f4((a), (b), (c), 0, 0, 0, 0x7F7F7F7F, 0, 0x7F7F7F7F)

// block 0: full histogram in LDS (dispatched FIRST so it hides under the
//   chunk blocks instead of straggling), plain final stores (no memset).
// blocks 1..1152: build fall chunks (one thread = one 16B chunk)
//   blocks 1..32 additionally zero S[4096]+P[4096]
__global__ __launch_bounds__(256) void prep_k(const float* __restrict__ centers,
                                              const float* __restrict__ feats,
                                              const float* __restrict__ ood,
                                              const int* __restrict__ targets,
                                              const int* __restrict__ pseudo,
                                              uint4* __restrict__ fall,
                                              unsigned* __restrict__ cnt,
                                              unsigned* __restrict__ cntT,
                                              float* __restrict__ SP) {
  __shared__ unsigned hc[1024];
  __shared__ unsigned hct[1024];
  const int tid = threadIdx.x;

  if (blockIdx.x > 0) {
    int idx  = (blockIdx.x - 1) * 256 + tid;  // 0 .. 294911 (16B chunks)
    int tile = idx >> 10;                     // 1024 chunks per 32-row tile
    int kq   = (idx >> 7) & 7;                // 128 chunks per kq-slab
    int p    = idx & 127;                     // physical chunk in slab
    int c    = p ^ ((p >> 3) & 7);            // logical chunk (involution)
    int lane = c >> 1;
    int row  = tile * 32 + (lane & 31);
    int k0   = kq * 64 + (lane >> 5) * 32 + (c & 1) * 16;

    const float* src = nullptr;
    if (row < NB)              src = feats   + (size_t)row * DK;
    else if (row < NB + NUM_C) src = centers + (size_t)(row - NB) * DK;
    else if (row < NCOL)       src = ood     + (size_t)(row - NB - NUM_C) * DK;
    uint4 out = make_uint4(0u, 0u, 0u, 0u);
    if (src) {
      float4 v0 = *(const float4*)(src + k0);
      float4 v1 = *(const float4*)(src + k0 + 4);
      float4 v2 = *(const float4*)(src + k0 + 8);
      float4 v3 = *(const float4*)(src + k0 + 12);
      int q;
      q = 0; q = cvt2<false>(v0.x, v0.y, q); q = cvt2<true>(v0.z, v0.w, q); out.x = (unsigned)q;
      q = 0; q = cvt2<false>(v1.x, v1.y, q); q = cvt2<true>(v1.z, v1.w, q); out.y = (unsigned)q;
      q = 0; q = cvt2<false>(v2.x, v2.y, q); q = cvt2<true>(v2.z, v2.w, q); out.z = (unsigned)q;
      q = 0; q = cvt2<false>(v3.x, v3.y, q); q = cvt2<true>(v3.z, v3.w, q); out.w = (unsigned)q;
    }
    fall[idx] = out;

    if (blockIdx.x <= 32)
      SP[(blockIdx.x - 1) * 256 + tid] = 0.0f;  // zeros S[4096] then P[4096]
  } else {
    // histogram block (first in dispatch order)
    for (int kk = tid; kk < 1024; kk += 256) { hc[kk] = 0u; hct[kk] = 0u; }
    __syncthreads();
    for (int i = tid; i < NB; i += 256) {
      int tt = targets[i];
      atomicAdd(&hc[tt], 1u);
      atomicAdd(&hct[tt], 1u);
      atomicAdd(&hc[pseudo[i]], 1u);
    }
    __syncthreads();
    for (int kk = tid; kk < 1024; kk += 256) {
      cnt[kk]  = hc[kk];
      cntT[kk] = hct[kk];
    }
  }
}

// Fused MX-fp8 GEMM, PERSISTENT 2-TILE blocks: 576 blocks, each owns ONE
// mTile (swz&31) and computes two nTiles (nT, nT+18). A is DMA'd into LDS
// ONCE per block and reused; the B ping-pong pipeline never drains across
// the tile boundary (K-loop kq=6,7 refill with the next tile's slabs 0,1,
// which then hide under the epilogue). 8 waves (2m x 4n), acc[2][2]/wave,
// operand-swapped MFMA so the j-reduction is in-lane; LDS row accumulators.
__global__ __launch_bounds__(512, 4) void gemm_fused(const unsigned char* __restrict__ fall,
                                                     const int* __restrict__ targets,
                                                     const int* __restrict__ pseudo,
                                                     const unsigned* __restrict__ cnt,
                                                     float* __restrict__ Sacc,
                                                     float* __restrict__ Pacc) {
  __shared__ unsigned char Alds[65536];   // 4 row-tiles of 32 (128 rows x 512 k)
  __shared__ int4   sTab[BN];             // x=lbl, y=rw0 bits, z=rw1 bits
  __shared__ int    sTgt[BM];
  __shared__ float  sS[BM];
  __shared__ float  sP[BM];

  const int tid  = threadIdx.x;
  // chunked XCD swizzle (576 = 8*72, bijective): per-XCD contiguous swz range
  // -> per-XCD L2 working set: A 2 MB + ~2.25 nT-pairs of B ~ 576 KB < 4 MiB
  int flat = (int)blockIdx.x;
  int swz  = (flat & 7) * 72 + (flat >> 3);
  const int mTile  = swz & 31;    // constant A tile for this block
  const int nT0    = swz >> 5;    // 0..17
  const int nT1    = nT0 + 18;    // 18..35
  const int lane   = tid & 63;
  const int wv     = tid >> 6;    // wave 0..7
  const int wm     = wv >> 2;     // row half: rows wm*64 .. +63
  const int wn     = wv & 3;      // col quarter: cols wn*64 .. +63

  // prologue: copy A (contiguous 64 KB of fall) into LDS via DMA (linear dest)
  {
    const unsigned char* aSrc = fall + (size_t)mTile * 65536;
#pragma unroll
    for (int i = 0; i < 8; i++)
      async16(aSrc + (i * 512 + tid) * 16, &Alds[(i * 512 + tid) * 16]);
  }

  // per-column tables for BOTH tiles (kept in regs; sTab holds current tile)
  int lblB = -1; float r0B = 0.f, r1B = 0.f;
  if (tid < BN) {
    // tile 0
    int j = nT0 * BN + tid;
    int lbl, tac;
    if (j < NB)            { tac = targets[j]; lbl = tac; }
    else if (j < NB+NUM_C) { tac = j - NB;     lbl = tac; }
    else                   { tac = pseudo[j - NB - NUM_C]; lbl = NUM_C; }
    float w  = (float)(1u + cnt[tac]);
    float r0 = 1.0f / w;
    float r1 = 1.0f / (w - 1.0f);
    sTab[tid] = make_int4(lbl, __float_as_int(r0), __float_as_int(r1), 0);
    // tile 1 (may run off NCOL at nT1 == 35)
    j = nT1 * BN + tid;
    int tac1;
    if (j >= NCOL)         { lblB = -1; tac1 = -1; }
    else if (j < NB)       { tac1 = targets[j]; lblB = tac1; }
    else if (j < NB+NUM_C) { tac1 = j - NB;     lblB = tac1; }
    else                   { tac1 = pseudo[j - NB - NUM_C]; lblB = NUM_C; }
    if (tac1 >= 0) {
      float w1 = (float)(1u + cnt[tac1]);
      r0B = 1.0f / w1;
      r1B = 1.0f / (w1 - 1.0f);
    }
  } else if (tid < BN + BM) {
    int i = tid - BN;
    sTgt[i] = targets[mTile * BM + i];
    sS[i] = 0.f;
    sP[i] = 0.f;
  }

  // swizzled per-lane chunk offsets within a 2048B kq-slab
  const int swzo = ((lane >> 2) & 7) << 4;
  const int off0 = (lane << 5) ^ swzo;
  const int off1 = off0 ^ 16;

  // B tile bases (this wave's col quarter) for both tiles
  const unsigned char* b0T0 = fall + (size_t)(nT0 * 8 + wn * 2) * 16384;
  const unsigned char* b1T0 = b0T0 + 16384;
  const unsigned char* b0T1 = fall + (size_t)(nT1 * 8 + wn * 2) * 16384;
  const unsigned char* b1T1 = b0T1 + 16384;

  // ping-pong B prefetch: fill slots with tile0 slabs 0,1
  uint4 bb[2][4];
#pragma unroll
  for (int s = 0; s < 2; s++) {
    const unsigned char* p0 = b0T0 + s * 2048;
    const unsigned char* p1 = b1T0 + s * 2048;
    bb[s][0] = *(const uint4*)(p0 + off0);
    bb[s][1] = *(const uint4*)(p0 + off1);
    bb[s][2] = *(const uint4*)(p1 + off0);
    bb[s][3] = *(const uint4*)(p1 + off1);
  }

  f32x16 acc00, acc01, acc10, acc11;
  f32x16 z;
#pragma unroll
  for (int t = 0; t < 16; t++) z[t] = 0.f;
  acc00 = z; acc01 = z; acc10 = z; acc11 = z;

  __syncthreads();   // A landed (vmcnt drain) + tables + sS/sP ready

  // K-loop: consume bb[kq&1]; kq<6 refills from current tile, kq=6,7 refill
  // with NEXT tile's slabs 0,1 (keeps the pipeline warm across the boundary)
#define KLOOP(C0, C1, N0, N1)                                              \
  _Pragma("unroll")                                                        \
  for (int kq = 0; kq < 8; kq++) {                                         \
    const int sl = kq & 1;                                                 \
    i32x8 bf0 = mk8(bb[sl][0], bb[sl][1]);                                 \
    i32x8 bf1 = mk8(bb[sl][2], bb[sl][3]);                                 \
    {                                                                      \
      const unsigned char* p0 = (kq < 6) ? (C0) + (kq + 2) * 2048          \
                                         : (N0) + (kq - 6) * 2048;         \
      const unsigned char* p1 = (kq < 6) ? (C1) + (kq + 2) * 2048          \
                                         : (N1) + (kq - 6) * 2048;         \
      bb[sl][0] = *(const uint4*)(p0 + off0);                              \
      bb[sl][1] = *(const uint4*)(p0 + off1);                              \
      bb[sl][2] = *(const uint4*)(p1 + off0);                              \
      bb[sl][3] = *(const uint4*)(p1 + off1);                              \
    }                                                                      \
    {                                                                      \
      const unsigned ao = (unsigned)(wm * 2 + 0) * 16384u + (unsigned)kq * 2048u; \
      uint4 al = *(const uint4*)&Alds[ao + off0];                          \
      uint4 ah = *(const uint4*)&Alds[ao + off1];                          \
      i32x8 af = mk8(al, ah);                                              \
      acc00 = MFMA_SC(bf0, af, acc00);                                     \
      acc01 = MFMA_SC(bf1, af, acc01);                                     \
    }                                                                      \
    {                                                                      \
      const unsigned ao = (unsigned)(wm * 2 + 1) * 16384u + (unsigned)kq * 2048u; \
      uint4 al = *(const uint4*)&Alds[ao + off0];                          \
      uint4 ah = *(const uint4*)&Alds[ao + off1];                          \
      i32x8 af = mk8(al, ah);                                              \
      acc10 = MFMA_SC(bf0, af, acc10);                                     \
      acc11 = MFMA_SC(bf1, af, acc11);                                     \
    }                                                                      \
  }

  // epilogue (swapped layout): lanes = i (col = lane&31), regs = j.
  // jl = wn*64 + nj*32 + (r&3) + 8*(r>>2) + 4*hh
#define EPILOGUE(NT)                                                       \
  {                                                                        \
    const int cq = lane & 31;                                              \
    const int hh = lane >> 5;                                              \
    const int iloc0 = wm * 64 + cq;                                        \
    const int iloc1 = iloc0 + 32;                                          \
    const int ig0 = mTile * BM + iloc0;                                    \
    const int ig1 = mTile * BM + iloc1;                                    \
    const int ti0 = sTgt[iloc0];                                           \
    const int ti1 = sTgt[iloc1];                                           \
    float s0 = 0.f, s1 = 0.f, p0a = 0.f, p1a = 0.f;                        \
    _Pragma("unroll")                                                      \
    for (int nj = 0; nj < 2; nj++) {                                       \
      _Pragma("unroll")                                                    \
      for (int r = 0; r < 16; r++) {                                       \
        int jl = wn * 64 + nj * 32 + (r & 3) + 8 * (r >> 2) + 4 * hh;      \
        int jg = (NT) * BN + jl;                                           \
        int4 tb = sTab[jl];                                                \
        float rw0 = __int_as_float(tb.y);                                  \
        float rw1 = __int_as_float(tb.z);                                  \
        float a0 = nj ? acc01[r] : acc00[r];                               \
        float a1 = nj ? acc11[r] : acc10[r];                               \
        {                                                                  \
          bool d = (jg == ig0);                                            \
          bool pp = (tb.x == ti0) && !d;                                   \
          float rw = d ? 0.f : (pp ? rw1 : rw0);                           \
          float e = __expf(fmaf(a0, INV_T, -INV_T));                       \
          s0 = fmaf(e, rw, s0);                                            \
          p0a += pp ? a0 : 0.f;                                            \
        }                                                                  \
        {                                                                  \
          bool d = (jg == ig1);                                            \
          bool pp = (tb.x == ti1) && !d;                                   \
          float rw = d ? 0.f : (pp ? rw1 : rw0);                           \
          float e = __expf(fmaf(a1, INV_T, -INV_T));                       \
          s1 = fmaf(e, rw, s1);                                            \
          p1a += pp ? a1 : 0.f;                                            \
        }                                                                  \
      }                                                                    \
    }                                                                      \
    atomicAdd(&sS[iloc0], s0);                                             \
    atomicAdd(&sP[iloc0], p0a * INV_T);                                    \
    atomicAdd(&sS[iloc1], s1);                                             \
    atomicAdd(&sP[iloc1], p1a * INV_T);                                    \
  }

  // ---- tile 0 ----
  KLOOP(b0T0, b1T0, b0T1, b1T1)      // tail refills = tile1 slabs 0,1
  EPILOGUE(nT0)
  __syncthreads();                    // epilogue0 LDS atomics done
  if (tid < BM) {
    int ig = mTile * BM + tid;
    atomicAdd(&Sacc[ig], sS[tid]);
    atomicAdd(&Pacc[ig], sP[tid]);
    sS[tid] = 0.f;
    sP[tid] = 0.f;
  }
  if (tid < BN)
    sTab[tid] = make_int4(lblB, __float_as_int(r0B), __float_as_int(r1B), 0);
  acc00 = z; acc01 = z; acc10 = z; acc11 = z;
  __syncthreads();                    // sS/sP rezeroed + sTab(t1) visible

  // ---- tile 1 ----
  KLOOP(b0T1, b1T1, b0T1, b1T1)      // tail refills harmless (discarded)
  EPILOGUE(nT1)
  __syncthreads();
  if (tid < BM) {
    int ig = mTile * BM + tid;
    atomicAdd(&Sacc[ig], sS[tid]);
    atomicAdd(&Pacc[ig], sP[tid]);
  }
#undef KLOOP
#undef EPILOGUE
}

// loss = -mean( P/npos - 10 - log S );  npos_i = cntT[targets[i]]
__global__ __launch_bounds__(256) void finalize_k(const float* __restrict__ S,
                                                  const float* __restrict__ P,
                                                  const int* __restrict__ targets,
                                                  const unsigned* __restrict__ cntT,
                                                  float* __restrict__ out) {
  __shared__ unsigned ct[1024];
  __shared__ float red[4];
  int tid = threadIdx.x;
  for (int k = tid; k < 1024; k += 256) ct[k] = cntT[k];
  __syncthreads();
  float local = 0.f;
  for (int i = tid; i < NB; i += 256) {
    float npos = (float)ct[targets[i]];
    local += P[i] / npos - INV_T - __logf(S[i]);
  }
  for (int m = 1; m < 64; m <<= 1) local += __shfl_xor(local, m, 64);
  if ((tid & 63) == 0) red[tid >> 6] = local;
  __syncthreads();
  if (tid == 0) {
    float t = red[0] + red[1] + red[2] + red[3];
    out[0] = -t / (float)NB;
  }
}

extern "C" void kernel_launch(void* const* d_in, const int* in_sizes, int n_in,
                              void* d_out, int out_size, void* d_ws, size_t ws_size,
                              hipStream_t stream) {
  const float* centers = (const float*)d_in[0];   // [1000][512] f32
  const float* feats   = (const float*)d_in[1];   // [4096][512] f32
  const int*   targets = (const int*)d_in[2];     // [4096] i32
  const float* ood     = (const float*)d_in[3];   // [4096][512] f32
  const int*   pseudo  = (const int*)d_in[4];     // [4096] i32

  char* ws = (char*)d_ws;
  uint4*    fall  = (uint4*)(ws + OFF_FALL);
  unsigned* cnt   = (unsigned*)(ws + OFF_CNT);
  unsigned* cntT  = (unsigned*)(ws + OFF_CNTT);
  float*    Sacc  = (float*)(ws + OFF_S);
  float*    Pacc  = (float*)(ws + OFF_P);

  prep_k<<<dim3(NCHUNKBLK + 1), 256, 0, stream>>>(centers, feats, ood, targets, pseudo,
                                                  fall, cnt, cntT, Sacc);
  gemm_fused<<<dim3(576), 512, 0, stream>>>((const unsigned char*)fall, targets,
                                            pseudo, cnt, Sacc, Pacc);
  finalize_k<<<1, 256, 0, stream>>>(Sacc, Pacc, targets, cntT, (float*)d_out);
}

// Round 7
// 123.491 us; speedup vs baseline: 1.5591x; 1.5591x over previous
//
#include <hip/hip_runtime.h>
#include <stdint.h>

// Problem constants
#define NUM_C 1000
#define NB    4096
#define NCOL  9192          // NB + NUM_C + NO
#define NPAD  9216          // 288 row-tiles of 32
#define DK    512
#define BM    128
#define BN    256
#define INV_T 10.0f

typedef __attribute__((ext_vector_type(16))) float f32x16;
typedef __attribute__((ext_vector_type(8)))  int   i32x8;

// fragment register block: load 2x16B directly into MFMA operand storage
union frag8 { i32x8 v; uint4 q[2]; };

// workspace layout (bytes)
// fall: MX fragment layout [tile=288][kq=8][chunk16B=128(swizzled)] = 4,718,592 B
//   lane l of a tile holds row (l&31), k = kq*64 + (l>>5)*32 + [0..31]
//   chunk swizzle within each 2048B kq-slab: phys p = c ^ ((c>>3)&7)  (involution)
#define OFF_FALL  0u
#define OFF_CNT   4718592u           // uint[1024] final hist (targets+pseudo)
#define OFF_CNTT  4722688u           // uint[1024] final hist (targets only)
#define OFF_S     4726784u           // float[4096]
#define OFF_P     4743168u           // float[4096]  (contiguous after S)

#define NCHUNKBLK 1152               // blocks doing fall chunks

__device__ __forceinline__ void async16(const void* g, void* l) {
  __builtin_amdgcn_global_load_lds((const __attribute__((address_space(1))) void*)g,
                                   (__attribute__((address_space(3))) void*)l,
                                   16, 0, 0);
}

// f32 -> e4m3fn (OCP), software RNE fallback
__device__ __forceinline__ unsigned sw_e4m3(float x) {
  float ax = fabsf(x);
  unsigned s = (__float_as_uint(x) >> 24) & 0x80u;
  if (ax < 0.015625f) {
    int n = (int)rintf(ax * 512.0f);
    if (n >= 8) return s | 0x08u;
    return s | (unsigned)n;
  }
  if (ax >= 448.0f) return s | 0x7Eu;
  unsigned u = __float_as_uint(ax);
  int ee = (int)(u >> 23) - 127;
  float scale = __uint_as_float((unsigned)(3 - ee + 127) << 23);
  int qv = (int)rintf(ax * scale);
  if (qv == 16) { ee++; qv = 8; }
  return s | (unsigned)(((ee + 7) << 3) | (qv - 8));
}

template <bool HI>
__device__ __forceinline__ int cvt2(float a, float b, int old) {
#if __has_builtin(__builtin_amdgcn_cvt_pk_fp8_f32)
  return __builtin_amdgcn_cvt_pk_fp8_f32(a, b, old, HI);
#else
  unsigned pk = sw_e4m3(a) | (sw_e4m3(b) << 8);
  return HI ? (int)(((unsigned)old & 0x0000FFFFu) | (pk << 16))
            : (int)(((unsigned)old & 0xFFFF0000u) | pk);
#endif
}

// MX-scaled fp8 MFMA, unit scales (e8m0 127 = 1.0): same products as plain fp8
#define MFMA_SC(a, b, c) \
  __builtin_amdgcn_mfma_scale_f32_32x32x64_f8f6f4((a), (b), (c), 0, 0, 0, 0x7F7F7F7F, 0, 0x7F7F7F7F)

// block 0: full histogram in LDS (dispatched FIRST so it hides under the
//   chunk blocks instead of straggling), plain final stores (no memset).
// blocks 1..1152: build fall chunks (one thread = one 16B chunk)
//   blocks 1..32 additionally zero S[4096]+P[4096]
__global__ __launch_bounds__(256) void prep_k(const float* __restrict__ centers,
                                              const float* __restrict__ feats,
                                              const float* __restrict__ ood,
                                              const int* __restrict__ targets,
                                              const int* __restrict__ pseudo,
                                              uint4* __restrict__ fall,
                                              unsigned* __restrict__ cnt,
                                              unsigned* __restrict__ cntT,
                                              float* __restrict__ SP) {
  __shared__ unsigned hc[1024];
  __shared__ unsigned hct[1024];
  const int tid = threadIdx.x;

  if (blockIdx.x > 0) {
    int idx  = (blockIdx.x - 1) * 256 + tid;  // 0 .. 294911 (16B chunks)
    int tile = idx >> 10;                     // 1024 chunks per 32-row tile
    int kq   = (idx >> 7) & 7;                // 128 chunks per kq-slab
    int p    = idx & 127;                     // physical chunk in slab
    int c    = p ^ ((p >> 3) & 7);            // logical chunk (involution)
    int lane = c >> 1;
    int row  = tile * 32 + (lane & 31);
    int k0   = kq * 64 + (lane >> 5) * 32 + (c & 1) * 16;

    const float* src = nullptr;
    if (row < NB)              src = feats   + (size_t)row * DK;
    else if (row < NB + NUM_C) src = centers + (size_t)(row - NB) * DK;
    else if (row < NCOL)       src = ood     + (size_t)(row - NB - NUM_C) * DK;
    uint4 out = make_uint4(0u, 0u, 0u, 0u);
    if (src) {
      float4 v0 = *(const float4*)(src + k0);
      float4 v1 = *(const float4*)(src + k0 + 4);
      float4 v2 = *(const float4*)(src + k0 + 8);
      float4 v3 = *(const float4*)(src + k0 + 12);
      int q;
      q = 0; q = cvt2<false>(v0.x, v0.y, q); q = cvt2<true>(v0.z, v0.w, q); out.x = (unsigned)q;
      q = 0; q = cvt2<false>(v1.x, v1.y, q); q = cvt2<true>(v1.z, v1.w, q); out.y = (unsigned)q;
      q = 0; q = cvt2<false>(v2.x, v2.y, q); q = cvt2<true>(v2.z, v2.w, q); out.z = (unsigned)q;
      q = 0; q = cvt2<false>(v3.x, v3.y, q); q = cvt2<true>(v3.z, v3.w, q); out.w = (unsigned)q;
    }
    fall[idx] = out;

    if (blockIdx.x <= 32)
      SP[(blockIdx.x - 1) * 256 + tid] = 0.0f;  // zeros S[4096] then P[4096]
  } else {
    // histogram block (first in dispatch order)
    for (int kk = tid; kk < 1024; kk += 256) { hc[kk] = 0u; hct[kk] = 0u; }
    __syncthreads();
    for (int i = tid; i < NB; i += 256) {
      int tt = targets[i];
      atomicAdd(&hc[tt], 1u);
      atomicAdd(&hct[tt], 1u);
      atomicAdd(&hc[pseudo[i]], 1u);
    }
    __syncthreads();
    for (int kk = tid; kk < 1024; kk += 256) {
      cnt[kk]  = hc[kk];
      cntT[kk] = hct[kk];
    }
  }
}

// Fused MX-fp8 GEMM 128x256, 8 waves (512 thr), 2m x 4n wave grid,
// acc 4x f32x16 per wave. OPERAND-SWAPPED MFMA (lanes = rows i, regs =
// cols j -> in-lane j-reduction). A tile (64 KB) in LDS via one prologue
// DMA; B direct from global, 2-deep ping-pong held in named frag8 unions
// loaded IN PLACE (no mk8 copies) -> K-loop liveness ~62 VGPR + 64 AGPR,
// fits the 128-reg cap of (512,4) with zero scratch spill (R6's 185 MB
// WRITE_SIZE was spill traffic from blowing this cap).
__global__ __launch_bounds__(512, 4) void gemm_fused(const unsigned char* __restrict__ fall,
                                                     const int* __restrict__ targets,
                                                     const int* __restrict__ pseudo,
                                                     const unsigned* __restrict__ cnt,
                                                     float* __restrict__ Sacc,
                                                     float* __restrict__ Pacc) {
  __shared__ unsigned char Alds[65536];   // 4 row-tiles of 32 (128 rows x 512 k)
  __shared__ int4   sTab[BN];             // x=lbl, y=rw0 bits, z=rw1 bits
  __shared__ int    sTgt[BM];
  __shared__ float  sS[BM];
  __shared__ float  sP[BM];

  const int tid  = threadIdx.x;
  // chunked XCD swizzle (1152 = 8*144, bijective)
  int flat = (int)blockIdx.y * 36 + (int)blockIdx.x;
  int swz  = (flat & 7) * 144 + (flat >> 3);
  const int nTile = swz >> 5;     // 0..35
  const int mTile = swz & 31;     // 0..31
  const int lane  = tid & 63;
  const int wv    = tid >> 6;     // wave 0..7
  const int wm    = wv >> 2;      // row half: rows wm*64 .. +63
  const int wn    = wv & 3;       // col quarter: cols wn*64 .. +63

  // prologue: copy A (contiguous 64 KB of fall) into LDS via DMA (linear dest)
  {
    const unsigned char* aSrc = fall + (size_t)mTile * 65536;
#pragma unroll
    for (int i = 0; i < 8; i++)
      async16(aSrc + (i * 512 + tid) * 16, &Alds[(i * 512 + tid) * 16]);
  }

  // per-column packed table (lbl, 1/w, 1/(w-1)); per-row targets; S/P init
  if (tid < BN) {
    int j = nTile * BN + tid;
    int lbl, tac;
    if (j >= NCOL)         { lbl = -1; tac = -1; }
    else if (j < NB)       { tac = targets[j]; lbl = tac; }
    else if (j < NB+NUM_C) { tac = j - NB;     lbl = tac; }
    else                   { tac = pseudo[j - NB - NUM_C]; lbl = NUM_C; }
    float r0 = 0.f, r1 = 0.f;
    if (tac >= 0) {
      float w = (float)(1u + cnt[tac]);
      r0 = 1.0f / w;
      r1 = 1.0f / (w - 1.0f);   // only selected when a positive exists => w>=2
    }
    sTab[tid] = make_int4(lbl, __float_as_int(r0), __float_as_int(r1), 0);
  } else if (tid < BN + BM) {
    int i = tid - BN;
    sTgt[i] = targets[mTile * BM + i];
    sS[i] = 0.f;
    sP[i] = 0.f;
  }

  // swizzled per-lane chunk offsets within a 2048B kq-slab
  const int swzo = ((lane >> 2) & 7) << 4;
  const int off0 = (lane << 5) ^ swzo;
  const int off1 = off0 ^ 16;

  // this wave's B tiles: cols nTile*256 + wn*64 + {0..31, 32..63}
  const unsigned char* bBase0 = fall + (size_t)(nTile * 8 + wn * 2) * 16384;
  const unsigned char* bBase1 = bBase0 + 16384;

  // 2-deep ping-pong, loaded in place (q[] static indices -> registers)
  frag8 b0p, b1p, b0q, b1q;
  b0p.q[0] = *(const uint4*)(bBase0 + off0);
  b0p.q[1] = *(const uint4*)(bBase0 + off1);
  b1p.q[0] = *(const uint4*)(bBase1 + off0);
  b1p.q[1] = *(const uint4*)(bBase1 + off1);
  b0q.q[0] = *(const uint4*)(bBase0 + 2048 + off0);
  b0q.q[1] = *(const uint4*)(bBase0 + 2048 + off1);
  b1q.q[0] = *(const uint4*)(bBase1 + 2048 + off0);
  b1q.q[1] = *(const uint4*)(bBase1 + 2048 + off1);

  f32x16 acc00, acc01, acc10, acc11;
  {
    f32x16 z;
#pragma unroll
    for (int t = 0; t < 16; t++) z[t] = 0.f;
    acc00 = z; acc01 = z; acc10 = z; acc11 = z;
  }

  const unsigned aRow0 = (unsigned)(wm * 2 + 0) * 16384u;
  const unsigned aRow1 = (unsigned)(wm * 2 + 1) * 16384u;

  __syncthreads();   // A landed (vmcnt drain) + tables + sS/sP ready

  // K-loop: 4 double-steps; even consumes P-regs (refill P<-kq+2),
  // odd consumes Q-regs (refill Q<-kq+3). All offsets compile-time.
#pragma unroll
  for (int k2 = 0; k2 < 4; k2++) {
    const unsigned ke = (unsigned)(2 * k2) * 2048u;
    const unsigned ko = ke + 2048u;
    // even step
    {
      frag8 a0, a1;
      a0.q[0] = *(const uint4*)&Alds[aRow0 + ke + off0];
      a0.q[1] = *(const uint4*)&Alds[aRow0 + ke + off1];
      a1.q[0] = *(const uint4*)&Alds[aRow1 + ke + off0];
      a1.q[1] = *(const uint4*)&Alds[aRow1 + ke + off1];
      acc00 = MFMA_SC(b0p.v, a0.v, acc00);
      acc01 = MFMA_SC(b1p.v, a0.v, acc01);
      acc10 = MFMA_SC(b0p.v, a1.v, acc10);
      acc11 = MFMA_SC(b1p.v, a1.v, acc11);
      if (k2 < 3) {
        b0p.q[0] = *(const uint4*)(bBase0 + (ke + 4096u) + off0);
        b0p.q[1] = *(const uint4*)(bBase0 + (ke + 4096u) + off1);
        b1p.q[0] = *(const uint4*)(bBase1 + (ke + 4096u) + off0);
        b1p.q[1] = *(const uint4*)(bBase1 + (ke + 4096u) + off1);
      }
    }
    // odd step
    {
      frag8 a0, a1;
      a0.q[0] = *(const uint4*)&Alds[aRow0 + ko + off0];
      a0.q[1] = *(const uint4*)&Alds[aRow0 + ko + off1];
      a1.q[0] = *(const uint4*)&Alds[aRow1 + ko + off0];
      a1.q[1] = *(const uint4*)&Alds[aRow1 + ko + off1];
      acc00 = MFMA_SC(b0q.v, a0.v, acc00);
      acc01 = MFMA_SC(b1q.v, a0.v, acc01);
      acc10 = MFMA_SC(b0q.v, a1.v, acc10);
      acc11 = MFMA_SC(b1q.v, a1.v, acc11);
      if (k2 < 3) {
        b0q.q[0] = *(const uint4*)(bBase0 + (ko + 4096u) + off0);
        b0q.q[1] = *(const uint4*)(bBase0 + (ko + 4096u) + off1);
        b1q.q[0] = *(const uint4*)(bBase1 + (ko + 4096u) + off0);
        b1q.q[1] = *(const uint4*)(bBase1 + (ko + 4096u) + off1);
      }
    }
  }

  // Epilogue (swapped layout): col = lane&31 = i within mi-tile;
  // reg r (+hh=lane>>5) = j: jl = wn*64 + nj*32 + (r&3) + 8*(r>>2) + 4*hh.
  // S_i += exp(l-10) * (diag?0 : pos?1/(w-1) : 1/w); P_i += pos?l:0 — in-lane.
  const int cq = lane & 31;
  const int hh = lane >> 5;
  const int iloc0 = wm * 64 + cq;          // mi = 0
  const int iloc1 = iloc0 + 32;            // mi = 1
  const int ig0 = mTile * BM + iloc0;
  const int ig1 = mTile * BM + iloc1;
  const int ti0 = sTgt[iloc0];
  const int ti1 = sTgt[iloc1];

  float s0 = 0.f, s1 = 0.f, p0 = 0.f, p1 = 0.f;
#pragma unroll
  for (int nj = 0; nj < 2; nj++) {
#pragma unroll
    for (int r = 0; r < 16; r++) {
      int jl = wn * 64 + nj * 32 + (r & 3) + 8 * (r >> 2) + 4 * hh;
      int jg = nTile * BN + jl;
      int4 tb = sTab[jl];
      float rw0 = __int_as_float(tb.y);
      float rw1 = __int_as_float(tb.z);
      float a0 = nj ? acc01[r] : acc00[r];
      float a1 = nj ? acc11[r] : acc10[r];
      {
        bool d = (jg == ig0);
        bool pp = (tb.x == ti0) && !d;
        float rw = d ? 0.f : (pp ? rw1 : rw0);
        float e = __expf(fmaf(a0, INV_T, -INV_T));
        s0 = fmaf(e, rw, s0);
        p0 += pp ? a0 : 0.f;
      }
      {
        bool d = (jg == ig1);
        bool pp = (tb.x == ti1) && !d;
        float rw = d ? 0.f : (pp ? rw1 : rw0);
        float e = __expf(fmaf(a1, INV_T, -INV_T));
        s1 = fmaf(e, rw, s1);
        p1 += pp ? a1 : 0.f;
      }
    }
  }
  // accumulate across (wn waves x hh halves) via LDS atomics (8 adders/addr)
  atomicAdd(&sS[iloc0], s0);
  atomicAdd(&sP[iloc0], p0 * INV_T);
  atomicAdd(&sS[iloc1], s1);
  atomicAdd(&sP[iloc1], p1 * INV_T);

  __syncthreads();
  if (tid < BM) {
    int ig = mTile * BM + tid;
    atomicAdd(&Sacc[ig], sS[tid]);
    atomicAdd(&Pacc[ig], sP[tid]);
  }
}

// loss = -mean( P/npos - 10 - log S );  npos_i = cntT[targets[i]]
__global__ __launch_bounds__(256) void finalize_k(const float* __restrict__ S,
                                                  const float* __restrict__ P,
                                                  const int* __restrict__ targets,
                                                  const unsigned* __restrict__ cntT,
                                                  float* __restrict__ out) {
  __shared__ unsigned ct[1024];
  __shared__ float red[4];
  int tid = threadIdx.x;
  for (int k = tid; k < 1024; k += 256) ct[k] = cntT[k];
  __syncthreads();
  float local = 0.f;
  for (int i = tid; i < NB; i += 256) {
    float npos = (float)ct[targets[i]];
    local += P[i] / npos - INV_T - __logf(S[i]);
  }
  for (int m = 1; m < 64; m <<= 1) local += __shfl_xor(local, m, 64);
  if ((tid & 63) == 0) red[tid >> 6] = local;
  __syncthreads();
  if (tid == 0) {
    float t = red[0] + red[1] + red[2] + red[3];
    out[0] = -t / (float)NB;
  }
}

extern "C" void kernel_launch(void* const* d_in, const int* in_sizes, int n_in,
                              void* d_out, int out_size, void* d_ws, size_t ws_size,
                              hipStream_t stream) {
  const float* centers = (const float*)d_in[0];   // [1000][512] f32
  const float* feats   = (const float*)d_in[1];   // [4096][512] f32
  const int*   targets = (const int*)d_in[2];     // [4096] i32
  const float* ood     = (const float*)d_in[3];   // [4096][512] f32
  const int*   pseudo  = (const int*)d_in[4];     // [4096] i32

  char* ws = (char*)d_ws;
  uint4*    fall  = (uint4*)(ws + OFF_FALL);
  unsigned* cnt   = (unsigned*)(ws + OFF_CNT);
  unsigned* cntT  = (unsigned*)(ws + OFF_CNTT);
  float*    Sacc  = (float*)(ws + OFF_S);
  float*    Pacc  = (float*)(ws + OFF_P);

  prep_k<<<dim3(NCHUNKBLK + 1), 256, 0, stream>>>(centers, feats, ood, targets, pseudo,
                                                  fall, cnt, cntT, Sacc);
  gemm_fused<<<dim3(NPAD / BN, NB / BM), 512, 0, stream>>>((const unsigned char*)fall, targets,
                                                           pseudo, cnt, Sacc, Pacc);
  finalize_k<<<1, 256, 0, stream>>>(Sacc, Pacc, targets, cntT, (float*)d_out);
}

// Round 8
// 120.290 us; speedup vs baseline: 1.6006x; 1.0266x over previous
//
#include <hip/hip_runtime.h>
#include <stdint.h>

// Problem constants
#define NUM_C 1000
#define NB    4096
#define NCOL  9192          // NB + NUM_C + NO
#define NPAD  9216          // 288 row-tiles of 32
#define DK    512
#define BM    128
#define BN    512
#define INV_T 10.0f

typedef __attribute__((ext_vector_type(16))) float f32x16;
typedef __attribute__((ext_vector_type(8)))  int   i32x8;

// fragment register block: load 2x16B directly into MFMA operand storage
union frag8 { i32x8 v; uint4 q[2]; };

// workspace layout (bytes)
// fall: MX fragment layout [tile=288][kq=8][chunk16B=128(swizzled)] = 4,718,592 B
//   lane l of a tile holds row (l&31), k = kq*64 + (l>>5)*32 + [0..31]
//   chunk swizzle within each 2048B kq-slab: phys p = c ^ ((c>>3)&7)  (involution)
#define OFF_FALL  0u
#define OFF_CNT   4718592u           // uint[1024] final hist (targets+pseudo)
#define OFF_CNTT  4722688u           // uint[1024] final hist (targets only)
#define OFF_S     4726784u           // float[4096]
#define OFF_P     4743168u           // float[4096]  (contiguous after S)

#define NCHUNKBLK 1152               // blocks doing fall chunks

__device__ __forceinline__ void async16(const void* g, void* l) {
  __builtin_amdgcn_global_load_lds((const __attribute__((address_space(1))) void*)g,
                                   (__attribute__((address_space(3))) void*)l,
                                   16, 0, 0);
}

// f32 -> e4m3fn (OCP), software RNE fallback
__device__ __forceinline__ unsigned sw_e4m3(float x) {
  float ax = fabsf(x);
  unsigned s = (__float_as_uint(x) >> 24) & 0x80u;
  if (ax < 0.015625f) {
    int n = (int)rintf(ax * 512.0f);
    if (n >= 8) return s | 0x08u;
    return s | (unsigned)n;
  }
  if (ax >= 448.0f) return s | 0x7Eu;
  unsigned u = __float_as_uint(ax);
  int ee = (int)(u >> 23) - 127;
  float scale = __uint_as_float((unsigned)(3 - ee + 127) << 23);
  int qv = (int)rintf(ax * scale);
  if (qv == 16) { ee++; qv = 8; }
  return s | (unsigned)(((ee + 7) << 3) | (qv - 8));
}

template <bool HI>
__device__ __forceinline__ int cvt2(float a, float b, int old) {
#if __has_builtin(__builtin_amdgcn_cvt_pk_fp8_f32)
  return __builtin_amdgcn_cvt_pk_fp8_f32(a, b, old, HI);
#else
  unsigned pk = sw_e4m3(a) | (sw_e4m3(b) << 8);
  return HI ? (int)(((unsigned)old & 0x0000FFFFu) | (pk << 16))
            : (int)(((unsigned)old & 0xFFFF0000u) | pk);
#endif
}

// MX-scaled fp8 MFMA, unit scales (e8m0 127 = 1.0): same products as plain fp8
#define MFMA_SC(a, b, c) \
  __builtin_amdgcn_mfma_scale_f32_32x32x64_f8f6f4((a), (b), (c), 0, 0, 0, 0x7F7F7F7F, 0, 0x7F7F7F7F)

// block 0: full histogram in LDS (dispatched FIRST), plain final stores.
// blocks 1..1152: build fall chunks (one thread = one 16B chunk)
//   blocks 1..32 additionally zero S[4096]+P[4096]
__global__ __launch_bounds__(256) void prep_k(const float* __restrict__ centers,
                                              const float* __restrict__ feats,
                                              const float* __restrict__ ood,
                                              const int* __restrict__ targets,
                                              const int* __restrict__ pseudo,
                                              uint4* __restrict__ fall,
                                              unsigned* __restrict__ cnt,
                                              unsigned* __restrict__ cntT,
                                              float* __restrict__ SP) {
  __shared__ unsigned hc[1024];
  __shared__ unsigned hct[1024];
  const int tid = threadIdx.x;

  if (blockIdx.x > 0) {
    int idx  = (blockIdx.x - 1) * 256 + tid;  // 0 .. 294911 (16B chunks)
    int tile = idx >> 10;                     // 1024 chunks per 32-row tile
    int kq   = (idx >> 7) & 7;                // 128 chunks per kq-slab
    int p    = idx & 127;                     // physical chunk in slab
    int c    = p ^ ((p >> 3) & 7);            // logical chunk (involution)
    int lane = c >> 1;
    int row  = tile * 32 + (lane & 31);
    int k0   = kq * 64 + (lane >> 5) * 32 + (c & 1) * 16;

    const float* src = nullptr;
    if (row < NB)              src = feats   + (size_t)row * DK;
    else if (row < NB + NUM_C) src = centers + (size_t)(row - NB) * DK;
    else if (row < NCOL)       src = ood     + (size_t)(row - NB - NUM_C) * DK;
    uint4 out = make_uint4(0u, 0u, 0u, 0u);
    if (src) {
      float4 v0 = *(const float4*)(src + k0);
      float4 v1 = *(const float4*)(src + k0 + 4);
      float4 v2 = *(const float4*)(src + k0 + 8);
      float4 v3 = *(const float4*)(src + k0 + 12);
      int q;
      q = 0; q = cvt2<false>(v0.x, v0.y, q); q = cvt2<true>(v0.z, v0.w, q); out.x = (unsigned)q;
      q = 0; q = cvt2<false>(v1.x, v1.y, q); q = cvt2<true>(v1.z, v1.w, q); out.y = (unsigned)q;
      q = 0; q = cvt2<false>(v2.x, v2.y, q); q = cvt2<true>(v2.z, v2.w, q); out.z = (unsigned)q;
      q = 0; q = cvt2<false>(v3.x, v3.y, q); q = cvt2<true>(v3.z, v3.w, q); out.w = (unsigned)q;
    }
    fall[idx] = out;

    if (blockIdx.x <= 32)
      SP[(blockIdx.x - 1) * 256 + tid] = 0.0f;  // zeros S[4096] then P[4096]
  } else {
    // histogram block (first in dispatch order)
    for (int kk = tid; kk < 1024; kk += 256) { hc[kk] = 0u; hct[kk] = 0u; }
    __syncthreads();
    for (int i = tid; i < NB; i += 256) {
      int tt = targets[i];
      atomicAdd(&hc[tt], 1u);
      atomicAdd(&hct[tt], 1u);
      atomicAdd(&hc[pseudo[i]], 1u);
    }
    __syncthreads();
    for (int kk = tid; kk < 1024; kk += 256) {
      cnt[kk]  = hc[kk];
      cntT[kk] = hct[kk];
    }
  }
}

// Fused MX-fp8 GEMM 128x512, 16 waves (1024 thr), 2m x 8n wave grid,
// per-wave 64 rows x 64 cols (acc 4x f32x16) -- K-loop identical to R7's.
// OPERAND-SWAPPED MFMA (lanes = rows i, regs = cols j -> in-lane j-reduce).
// A tile (64 KB) in LDS via one prologue DMA; B direct from global, 2-deep
// ping-pong in named frag8 unions (no copies, no spill at the 128-reg cap).
// Epilogue is ATOMIC-FREE: hh-combine via shfl_xor(32), one plain ds_write
// per (wn,row) slot into per-wn slices, tid<128 sums 8 slices -> 1 global
// atomic per row. 576 blocks (halved prologue/epilogue/barrier instances,
// halved A traffic vs the 1152-block version).
__global__ __launch_bounds__(1024, 4) void gemm_fused(const unsigned char* __restrict__ fall,
                                                      const int* __restrict__ targets,
                                                      const int* __restrict__ pseudo,
                                                      const unsigned* __restrict__ cnt,
                                                      float* __restrict__ Sacc,
                                                      float* __restrict__ Pacc) {
  __shared__ unsigned char Alds[65536];   // 4 row-tiles of 32 (128 rows x 512 k)
  __shared__ int4   sTab[BN];             // x=lbl, y=rw0 bits, z=rw1 bits
  __shared__ int    sTgt[BM];
  __shared__ float  sSw[8][BM];           // per-wn S slices (each slot written once)
  __shared__ float  sPw[8][BM];

  const int tid  = threadIdx.x;
  // chunked XCD swizzle (576 = 8*72, bijective)
  int flat = (int)blockIdx.x;
  int swz  = (flat & 7) * 72 + (flat >> 3);
  const int nTile = swz >> 5;     // 0..17
  const int mTile = swz & 31;     // 0..31
  const int lane  = tid & 63;
  const int wv    = tid >> 6;     // wave 0..15
  const int wm    = wv & 1;       // row half: rows wm*64 .. +63
  const int wn    = wv >> 1;      // col eighth: cols wn*64 .. +63

  // prologue: copy A (contiguous 64 KB of fall) into LDS via DMA (linear dest)
  {
    const unsigned char* aSrc = fall + (size_t)mTile * 65536;
#pragma unroll
    for (int i = 0; i < 4; i++)
      async16(aSrc + (i * 1024 + tid) * 16, &Alds[(i * 1024 + tid) * 16]);
  }

  // per-column packed table (lbl, 1/w, 1/(w-1)); per-row targets
  if (tid < BN) {
    int j = nTile * BN + tid;
    int lbl, tac;
    if (j >= NCOL)         { lbl = -1; tac = -1; }
    else if (j < NB)       { tac = targets[j]; lbl = tac; }
    else if (j < NB+NUM_C) { tac = j - NB;     lbl = tac; }
    else                   { tac = pseudo[j - NB - NUM_C]; lbl = NUM_C; }
    float r0 = 0.f, r1 = 0.f;
    if (tac >= 0) {
      float w = (float)(1u + cnt[tac]);
      r0 = 1.0f / w;
      r1 = 1.0f / (w - 1.0f);   // only selected when a positive exists => w>=2
    }
    sTab[tid] = make_int4(lbl, __float_as_int(r0), __float_as_int(r1), 0);
  } else if (tid < BN + BM) {
    sTgt[tid - BN] = targets[mTile * BM + (tid - BN)];
  }

  // swizzled per-lane chunk offsets within a 2048B kq-slab
  const int swzo = ((lane >> 2) & 7) << 4;
  const int off0 = (lane << 5) ^ swzo;
  const int off1 = off0 ^ 16;

  // this wave's B tiles: cols nTile*512 + wn*64 + {0..31, 32..63}
  const unsigned char* bBase0 = fall + (size_t)(nTile * 16 + wn * 2) * 16384;
  const unsigned char* bBase1 = bBase0 + 16384;

  // 2-deep ping-pong, loaded in place (q[] static indices -> registers)
  frag8 b0p, b1p, b0q, b1q;
  b0p.q[0] = *(const uint4*)(bBase0 + off0);
  b0p.q[1] = *(const uint4*)(bBase0 + off1);
  b1p.q[0] = *(const uint4*)(bBase1 + off0);
  b1p.q[1] = *(const uint4*)(bBase1 + off1);
  b0q.q[0] = *(const uint4*)(bBase0 + 2048 + off0);
  b0q.q[1] = *(const uint4*)(bBase0 + 2048 + off1);
  b1q.q[0] = *(const uint4*)(bBase1 + 2048 + off0);
  b1q.q[1] = *(const uint4*)(bBase1 + 2048 + off1);

  f32x16 acc00, acc01, acc10, acc11;
  {
    f32x16 z;
#pragma unroll
    for (int t = 0; t < 16; t++) z[t] = 0.f;
    acc00 = z; acc01 = z; acc10 = z; acc11 = z;
  }

  const unsigned aRow0 = (unsigned)(wm * 2 + 0) * 16384u;
  const unsigned aRow1 = (unsigned)(wm * 2 + 1) * 16384u;

  __syncthreads();   // A landed (vmcnt drain) + tables ready

  // K-loop: 4 double-steps; even consumes P-regs (refill P<-kq+2),
  // odd consumes Q-regs (refill Q<-kq+3). All offsets compile-time.
#pragma unroll
  for (int k2 = 0; k2 < 4; k2++) {
    const unsigned ke = (unsigned)(2 * k2) * 2048u;
    const unsigned ko = ke + 2048u;
    // even step
    {
      frag8 a0, a1;
      a0.q[0] = *(const uint4*)&Alds[aRow0 + ke + off0];
      a0.q[1] = *(const uint4*)&Alds[aRow0 + ke + off1];
      a1.q[0] = *(const uint4*)&Alds[aRow1 + ke + off0];
      a1.q[1] = *(const uint4*)&Alds[aRow1 + ke + off1];
      acc00 = MFMA_SC(b0p.v, a0.v, acc00);
      acc01 = MFMA_SC(b1p.v, a0.v, acc01);
      acc10 = MFMA_SC(b0p.v, a1.v, acc10);
      acc11 = MFMA_SC(b1p.v, a1.v, acc11);
      if (k2 < 3) {
        b0p.q[0] = *(const uint4*)(bBase0 + (ke + 4096u) + off0);
        b0p.q[1] = *(const uint4*)(bBase0 + (ke + 4096u) + off1);
        b1p.q[0] = *(const uint4*)(bBase1 + (ke + 4096u) + off0);
        b1p.q[1] = *(const uint4*)(bBase1 + (ke + 4096u) + off1);
      }
    }
    // odd step
    {
      frag8 a0, a1;
      a0.q[0] = *(const uint4*)&Alds[aRow0 + ko + off0];
      a0.q[1] = *(const uint4*)&Alds[aRow0 + ko + off1];
      a1.q[0] = *(const uint4*)&Alds[aRow1 + ko + off0];
      a1.q[1] = *(const uint4*)&Alds[aRow1 + ko + off1];
      acc00 = MFMA_SC(b0q.v, a0.v, acc00);
      acc01 = MFMA_SC(b1q.v, a0.v, acc01);
      acc10 = MFMA_SC(b0q.v, a1.v, acc10);
      acc11 = MFMA_SC(b1q.v, a1.v, acc11);
      if (k2 < 3) {
        b0q.q[0] = *(const uint4*)(bBase0 + (ko + 4096u) + off0);
        b0q.q[1] = *(const uint4*)(bBase0 + (ko + 4096u) + off1);
        b1q.q[0] = *(const uint4*)(bBase1 + (ko + 4096u) + off0);
        b1q.q[1] = *(const uint4*)(bBase1 + (ko + 4096u) + off1);
      }
    }
  }

  // Epilogue (swapped layout): col = lane&31 = i within mi-tile;
  // reg r (+hh=lane>>5) = j: jl = wn*64 + nj*32 + (r&3) + 8*(r>>2) + 4*hh.
  // S_i += exp(l-10) * (diag?0 : pos?1/(w-1) : 1/w); P_i += pos?l:0 — in-lane.
  const int cq = lane & 31;
  const int hh = lane >> 5;
  const int iloc0 = wm * 64 + cq;          // mi = 0
  const int iloc1 = iloc0 + 32;            // mi = 1
  const int ig0 = mTile * BM + iloc0;
  const int ig1 = mTile * BM + iloc1;
  const int ti0 = sTgt[iloc0];
  const int ti1 = sTgt[iloc1];

  float s0 = 0.f, s1 = 0.f, p0 = 0.f, p1 = 0.f;
#pragma unroll
  for (int nj = 0; nj < 2; nj++) {
#pragma unroll
    for (int r = 0; r < 16; r++) {
      int jl = wn * 64 + nj * 32 + (r & 3) + 8 * (r >> 2) + 4 * hh;
      int jg = nTile * BN + jl;
      int4 tb = sTab[jl];
      float rw0 = __int_as_float(tb.y);
      float rw1 = __int_as_float(tb.z);
      float a0 = nj ? acc01[r] : acc00[r];
      float a1 = nj ? acc11[r] : acc10[r];
      {
        bool d = (jg == ig0);
        bool pp = (tb.x == ti0) && !d;
        float rw = d ? 0.f : (pp ? rw1 : rw0);
        float e = __expf(fmaf(a0, INV_T, -INV_T));
        s0 = fmaf(e, rw, s0);
        p0 += pp ? a0 : 0.f;
      }
      {
        bool d = (jg == ig1);
        bool pp = (tb.x == ti1) && !d;
        float rw = d ? 0.f : (pp ? rw1 : rw0);
        float e = __expf(fmaf(a1, INV_T, -INV_T));
        s1 = fmaf(e, rw, s1);
        p1 += pp ? a1 : 0.f;
      }
    }
  }
  // combine hh halves in-register, then ONE plain ds_write per slot:
  // slot (wn, row) is written by exactly one lane of exactly one wave.
  s0 += __shfl_xor(s0, 32, 64);
  s1 += __shfl_xor(s1, 32, 64);
  p0 += __shfl_xor(p0, 32, 64);
  p1 += __shfl_xor(p1, 32, 64);
  if (hh == 0) {
    sSw[wn][iloc0] = s0;
    sSw[wn][iloc1] = s1;
    sPw[wn][iloc0] = p0 * INV_T;
    sPw[wn][iloc1] = p1 * INV_T;
  }

  __syncthreads();
  if (tid < BM) {
    float S = 0.f, P = 0.f;
#pragma unroll
    for (int w = 0; w < 8; w++) { S += sSw[w][tid]; P += sPw[w][tid]; }
    int ig = mTile * BM + tid;
    atomicAdd(&Sacc[ig], S);
    atomicAdd(&Pacc[ig], P);
  }
}

// loss = -mean( P/npos - 10 - log S );  npos_i = cntT[targets[i]]
__global__ __launch_bounds__(256) void finalize_k(const float* __restrict__ S,
                                                  const float* __restrict__ P,
                                                  const int* __restrict__ targets,
                                                  const unsigned* __restrict__ cntT,
                                                  float* __restrict__ out) {
  __shared__ unsigned ct[1024];
  __shared__ float red[4];
  int tid = threadIdx.x;
  for (int k = tid; k < 1024; k += 256) ct[k] = cntT[k];
  __syncthreads();
  float local = 0.f;
  for (int i = tid; i < NB; i += 256) {
    float npos = (float)ct[targets[i]];
    local += P[i] / npos - INV_T - __logf(S[i]);
  }
  for (int m = 1; m < 64; m <<= 1) local += __shfl_xor(local, m, 64);
  if ((tid & 63) == 0) red[tid >> 6] = local;
  __syncthreads();
  if (tid == 0) {
    float t = red[0] + red[1] + red[2] + red[3];
    out[0] = -t / (float)NB;
  }
}

extern "C" void kernel_launch(void* const* d_in, const int* in_sizes, int n_in,
                              void* d_out, int out_size, void* d_ws, size_t ws_size,
                              hipStream_t stream) {
  const float* centers = (const float*)d_in[0];   // [1000][512] f32
  const float* feats   = (const float*)d_in[1];   // [4096][512] f32
  const int*   targets = (const int*)d_in[2];     // [4096] i32
  const float* ood     = (const float*)d_in[3];   // [4096][512] f32
  const int*   pseudo  = (const int*)d_in[4];     // [4096] i32

  char* ws = (char*)d_ws;
  uint4*    fall  = (uint4*)(ws + OFF_FALL);
  unsigned* cnt   = (unsigned*)(ws + OFF_CNT);
  unsigned* cntT  = (unsigned*)(ws + OFF_CNTT);
  float*    Sacc  = (float*)(ws + OFF_S);
  float*    Pacc  = (float*)(ws + OFF_P);

  prep_k<<<dim3(NCHUNKBLK + 1), 256, 0, stream>>>(centers, feats, ood, targets, pseudo,
                                                  fall, cnt, cntT, Sacc);
  gemm_fused<<<dim3((NPAD / BN) * (NB / BM)), 1024, 0, stream>>>((const unsigned char*)fall,
                                                                 targets, pseudo, cnt,
                                                                 Sacc, Pacc);
  finalize_k<<<1, 256, 0, stream>>>(Sacc, Pacc, targets, cntT, (float*)d_out);
}